// Round 5
// baseline (440.236 us; speedup 1.0000x reference)
//
#include <hip/hip_runtime.h>
#include <stdint.h>

// ================= problem constants =================
#define NB 8
#define TLEN 661376              // samples per batch
#define NFR 5152                 // frames
#define NFREQ 1025
#define NMEL 128
#define NFRP 5376                // padded frames (21 * 256)
#define OUT_BT (NMEL * NFR)

typedef unsigned int u32;
typedef float f32x4 __attribute__((ext_vector_type(4)));
typedef short s16x8 __attribute__((ext_vector_type(8)));
typedef u32 u32x4 __attribute__((ext_vector_type(4)));

__device__ __forceinline__ u32 f2bf(float f) {
  u32 u = __float_as_uint(f);
  return (u + 0x7FFFu + ((u >> 16) & 1u)) >> 16;   // RNE
}
__device__ __forceinline__ u32 packbf(float a, float b) {
  return f2bf(a) | (f2bf(b) << 16);
}
// Raw barrier with explicit LDS drain; keeps global prefetch loads in flight.
__device__ __forceinline__ void bar_lgkm() {
  asm volatile("s_waitcnt lgkmcnt(0)" ::: "memory");
  __builtin_amdgcn_s_barrier();
  __builtin_amdgcn_sched_barrier(0);
}

// ================= decoupled-path workspace =================
// W canonical: [g 0..8][k 0..63][fr 0..15][l4 0..3][l15 0..15][16B]
#define WCAN_BYTES 9437184        // 9*64*16*1024
#define MCAN_OFF   9437184
#define MCAN_BYTES 294912         // 36*8*1024
#define P_OFF      9732096
#define P_ROWB     2304           // 1152 freqs * 2B
// tiers
#define TIER1_NEED 108822528ULL   // P t-capacity 5376 (1 chunk)
#define TIER2_NEED 61636608ULL    // 2816 (2 chunks)
#define TIER3_NEED 42762240ULL    // 1792 (3 chunks)

// ---- prep: cos/sin fp32 -> bf16 canonical MFMA-A fragments ----
__global__ void prep_wcan(const float* __restrict__ cw, const float* __restrict__ sw,
                          char* __restrict__ wg) {
  int id = blockIdx.x * 256 + threadIdx.x;         // one u32 each
  int jp = id & 3, l15 = (id >> 2) & 15, l4 = (id >> 6) & 3;
  int fr = (id >> 8) & 15, k = (id >> 12) & 63, g = id >> 18;
  if (g >= 9) return;
  int freq = g * 128 + (fr >> 1) * 16 + l15;
  const float* src = (fr & 1) ? sw : cw;
  u32 pk = 0;
  if (freq < NFREQ) {
    int smp = k * 32 + l4 * 8 + jp * 2;
    pk = packbf(src[(size_t)freq * 2048 + smp], src[(size_t)freq * 2048 + smp + 1]);
  }
  *(u32*)(wg + (size_t)id * 4) = pk;
  // note: id*4 equals (((g*64+k)*16+fr)*1024 + l4*256 + l15*16 + jp*4) by construction
}

// ---- prep: mel fp32 -> bf16 canonical fragments [ks 0..35][fr 0..7][l4][l15][16B] ----
__global__ void prep_mcan(const float* __restrict__ mw, char* __restrict__ mg) {
  int id = blockIdx.x * 256 + threadIdx.x;
  if (id >= 73728) return;
  int jp = id & 3, l15 = (id >> 2) & 15, l4 = (id >> 6) & 3;
  int fr = (id >> 8) & 7, ks = id >> 11;
  int m = fr * 16 + l15;
  int f = ks * 32 + l4 * 8 + jp * 2;
  float v0 = (f < NFREQ) ? mw[(size_t)m * NFREQ + f] : 0.f;
  float v1 = (f + 1 < NFREQ) ? mw[(size_t)m * NFREQ + f + 1] : 0.f;
  *(u32*)(mg + (size_t)id * 4) = packbf(v0, v1);
}

// ================= K1: power spectrum =================
// grid (tb, 9, 8), 512 threads. Block: 256 W-rows x 256 frames.
// LDS: x 69376 B + W 3-deep ring 3*16384 = 118528 B (1 block/CU).
// Pipeline: MFMA(k) issues at barrier-exit with ZERO LDS wait (frags preloaded);
// frag reads(k+1), slab write(k+2), global load(k+3) hide under the MFMA pipe.
#define K1_X 69376
#define K1_LDS 118528
__global__ __launch_bounds__(512, 2) void k1_power(
    const float* __restrict__ x, const char* __restrict__ wg,
    char* __restrict__ P, int tstart, int tcap) {
  __shared__ __align__(16) char smem[K1_LDS];
  const int tid = threadIdx.x;
  const int lane = tid & 63, wid = tid >> 6;
  const int l15 = lane & 15, l4 = lane >> 4;
  const int fw = wid & 3, tw = wid >> 2;           // freq-wave, t-wave
  const int tb = blockIdx.x, g = blockIdx.y, b = blockIdx.z;
  const int t0 = tstart + tb * 256;

  // ---- stage x tile fp32->bf16, XOR swizzle on logical byte addr ----
  {
    const float* xb = x + (size_t)b * TLEN;
    const int sbase = t0 * 128;
#pragma unroll
    for (int i = 0; i < 9; ++i) {
      int q = tid + i * 512;
      if (q < 4336) {
        int s0 = sbase + q * 8;
        u32 r0, r1, r2, r3;
        if (s0 + 8 <= TLEN) {
          f32x4 v0 = *(const f32x4*)(xb + s0);
          f32x4 v1 = *(const f32x4*)(xb + s0 + 4);
          r0 = packbf(v0[0], v0[1]); r1 = packbf(v0[2], v0[3]);
          r2 = packbf(v1[0], v1[1]); r3 = packbf(v1[2], v1[3]);
        } else {
          float e[8];
#pragma unroll
          for (int j = 0; j < 8; ++j) { int s = s0 + j; e[j] = (s < TLEN) ? xb[s] : 0.f; }
          r0 = packbf(e[0], e[1]); r1 = packbf(e[2], e[3]);
          r2 = packbf(e[4], e[5]); r3 = packbf(e[6], e[7]);
        }
        int lb = q * 16;
        *(u32x4*)(smem + (lb ^ (((lb >> 8) & 7) << 4))) = (u32x4){r0, r1, r2, r3};
      }
    }
  }

  f32x4 acc[4][8];
#pragma unroll
  for (int i = 0; i < 4; ++i)
#pragma unroll
    for (int j = 0; j < 8; ++j) acc[i][j] = (f32x4){0.f, 0.f, 0.f, 0.f};

  const char* wslab = wg + (size_t)g * (64 * 16384);
  char* ring = smem + K1_X;

  // precomputed x-frag address pieces
  int bfbase[8], bfkey[8];
#pragma unroll
  for (int nt = 0; nt < 8; ++nt) {
    int lt = tw * 128 + nt * 16 + l15;
    bfbase[nt] = lt * 256 + l4 * 16;
    bfkey[nt] = lt & 7;
  }
  const int afoff = (fw * 4) * 1024 + l4 * 256 + l15 * 16;

  // ---- prologue: slabs 0,1 -> ring; slab 2 -> regs; frags(0) -> regs ----
  {
    u32x4 a0 = *(const u32x4*)(wslab + tid * 16);
    u32x4 a1 = *(const u32x4*)(wslab + tid * 16 + 8192);
    u32x4 b0 = *(const u32x4*)(wslab + 16384 + tid * 16);
    u32x4 b1 = *(const u32x4*)(wslab + 16384 + tid * 16 + 8192);
    *(u32x4*)(ring + tid * 16) = a0;
    *(u32x4*)(ring + tid * 16 + 8192) = a1;
    *(u32x4*)(ring + 16384 + tid * 16) = b0;
    *(u32x4*)(ring + 16384 + tid * 16 + 8192) = b1;
  }
  u32x4 wr0 = *(const u32x4*)(wslab + 2 * 16384 + tid * 16);
  u32x4 wr1 = *(const u32x4*)(wslab + 2 * 16384 + tid * 16 + 8192);
  bar_lgkm();                                       // x + slabs 0,1 visible

  s16x8 af[4], bf[8];
#pragma unroll
  for (int m4 = 0; m4 < 4; ++m4)
    af[m4] = *(const s16x8*)(ring + afoff + m4 * 1024);
#pragma unroll
  for (int nt = 0; nt < 8; ++nt)
    bf[nt] = *(const s16x8*)(smem + (bfbase[nt] ^ ((bfkey[nt] & 7) << 4)));

  int rd_n = 16384, wr_n = 32768;                   // ring offsets for k+1 read / k+2 write
  for (int k = 0; k < 64; ++k) {
    // 1. MFMA(k): operands already in regs (compiler waits lgkm for prologue/last-iter reads)
    __builtin_amdgcn_s_setprio(1);
#pragma unroll
    for (int m4 = 0; m4 < 4; ++m4)
#pragma unroll
      for (int nt = 0; nt < 8; ++nt)
        acc[m4][nt] = __builtin_amdgcn_mfma_f32_16x16x32_bf16(af[m4], bf[nt],
                                                              acc[m4][nt], 0, 0, 0);
    __builtin_amdgcn_s_setprio(0);

    // 2. frag reads for k+1 (same regs: MFMA already issued, WAR-safe)
    if (k + 1 < 64) {
      const char* rb = ring + rd_n;
#pragma unroll
      for (int m4 = 0; m4 < 4; ++m4)
        af[m4] = *(const s16x8*)(rb + afoff + m4 * 1024);
      const int kn = k + 1, kq = kn >> 2;
#pragma unroll
      for (int nt = 0; nt < 8; ++nt) {
        int a = bfbase[nt] + kn * 64;
        bf[nt] = *(const s16x8*)(smem + (a ^ (((bfkey[nt] + kq) & 7) << 4)));
      }
    }
    // 3. commit prefetched slab k+2 into ring (vmcnt wait auto; issued 1 iter ago)
    if (k + 2 < 64) {
      char* wb = ring + wr_n;
      *(u32x4*)(wb + tid * 16) = wr0;
      *(u32x4*)(wb + tid * 16 + 8192) = wr1;
    }
    // 4. issue global load of slab k+3
    if (k + 3 < 64) {
      const char* ns = wslab + (k + 3) * 16384;
      wr0 = *(const u32x4*)(ns + tid * 16);
      wr1 = *(const u32x4*)(ns + tid * 16 + 8192);
    }
    // rotate ring pointers
    rd_n += 16384; if (rd_n == 49152) rd_n = 0;
    wr_n += 16384; if (wr_n == 49152) wr_n = 0;
    // 5. one barrier per iter: slab(k+2) visible, frags(k+1) drained
    bar_lgkm();
  }

  // ---- P = c^2+s^2 -> bf16 -> LDS (reuse ring region) -> global [t][f] ----
  char* plds = smem + K1_X;
#pragma unroll
  for (int h = 0; h < 2; ++h) {
    if (tw == h) {
#pragma unroll
      for (int q = 0; q < 2; ++q)
#pragma unroll
        for (int nt = 0; nt < 8; ++nt) {
          f32x4 c = acc[q * 2][nt], s = acc[q * 2 + 1][nt];
          float p0 = c[0] * c[0] + s[0] * s[0];
          float p1 = c[1] * c[1] + s[1] * s[1];
          float p2 = c[2] * c[2] + s[2] * s[2];
          float p3 = c[3] * c[3] + s[3] * s[3];
          int lt = nt * 16 + l15;                   // row within this 128-t half
          int fl = fw * 32 + q * 16 + l4 * 4;
          int a = lt * 256 + fl * 2;
          int sw = (lt & 7) << 4;
          *(u32*)(plds + (a ^ sw)) = packbf(p0, p1);
          *(u32*)(plds + ((a + 4) ^ sw)) = packbf(p2, p3);
        }
    }
    bar_lgkm();
#pragma unroll
    for (int i = 0; i < 4; ++i) {
      int lin = (tid + i * 512) * 16;
      u32x4 v = *(const u32x4*)(plds + (lin ^ (((lin >> 8) & 7) << 4)));
      int tc = tb * 256 + h * 128 + (lin >> 8);
      *(u32x4*)(P + ((size_t)b * tcap + tc) * P_ROWB + g * 256 + (lin & 255)) = v;
    }
    bar_lgkm();
  }
}

// ================= K2: mel GEMM =================
// grid (tb64, 8), 256 threads (4 waves, m-split). Block: 128 m x 64 t, K = 1152.
__global__ __launch_bounds__(256, 4) void k2_mel(
    const char* __restrict__ P, const char* __restrict__ mg,
    float* __restrict__ out, int tstart, int tcap) {
  __shared__ __align__(16) char sm[4096];
  const int tid = threadIdx.x;
  const int lane = tid & 63, wid = tid >> 6;
  const int l15 = lane & 15, l4 = lane >> 4;
  const int tb = blockIdx.x, b = blockIdx.y;
  const int tz = tb * 64;                           // chunk-local t base

  const int st_t = tid >> 2, st_fo = tid & 3;       // staging map: 64t x 4 granules
  const char* prow = P + ((size_t)b * tcap + tz + st_t) * P_ROWB + st_fo * 16;

  f32x4 acc[2][4];
#pragma unroll
  for (int i = 0; i < 2; ++i)
#pragma unroll
    for (int j = 0; j < 4; ++j) acc[i][j] = (f32x4){0.f, 0.f, 0.f, 0.f};

  u32x4 pr = *(const u32x4*)prow;
  const int lw = (st_t * 64 + st_fo * 16) ^ ((st_t & 7) << 4);
  const int afo = l4 * 256 + l15 * 16;

  for (int ks = 0; ks < 36; ++ks) {
    *(u32x4*)(sm + lw) = pr;
    bar_lgkm();
    if (ks + 1 < 36) pr = *(const u32x4*)(prow + (ks + 1) * 64);
    s16x8 a0 = *(const s16x8*)(mg + (size_t)(ks * 8 + wid * 2) * 1024 + afo);
    s16x8 a1 = *(const s16x8*)(mg + (size_t)(ks * 8 + wid * 2 + 1) * 1024 + afo);
    s16x8 bf[4];
#pragma unroll
    for (int nt = 0; nt < 4; ++nt) {
      int a = ((nt * 16 + l15) * 64 + l4 * 16) ^ ((l15 & 7) << 4);
      bf[nt] = *(const s16x8*)(sm + a);
    }
#pragma unroll
    for (int nt = 0; nt < 4; ++nt) {
      acc[0][nt] = __builtin_amdgcn_mfma_f32_16x16x32_bf16(a0, bf[nt], acc[0][nt], 0, 0, 0);
      acc[1][nt] = __builtin_amdgcn_mfma_f32_16x16x32_bf16(a1, bf[nt], acc[1][nt], 0, 0, 0);
    }
    bar_lgkm();
  }

#pragma unroll
  for (int nt = 0; nt < 4; ++nt) {
    int t = tstart + tz + nt * 16 + l15;
    if (t < NFR) {
#pragma unroll
      for (int mf = 0; mf < 2; ++mf)
#pragma unroll
        for (int ii = 0; ii < 4; ++ii) {
          int m = wid * 32 + mf * 16 + l4 * 4 + ii;
          out[(size_t)b * OUT_BT + (size_t)m * NFR + t] = acc[mf][nt][ii];
        }
    }
  }
}

// ======================================================================
// ================= fused fallback (R3, proven) ========================
// ======================================================================
#define F_BT 96
#define F_NTT 54
#define F_NGRP 17
#define F_GI_TOT 1088
#define F_SLABB 8192
#define F_XSB 28416
#define F_XS_OFF 0
#define F_WL_OFF 28416
#define F_PL_OFF 36608
#define F_ML_OFF 48896
#define F_LDS_TOT 65280
#define F_WS_MG 8912896
#define F_WS_NEED 9191424
#define F_MLB 16384

__device__ __forceinline__ int f_swzW(int a) { return a ^ (((a >> 6) & 7) << 4); }
__device__ __forceinline__ int f_swzR(int a) { return a ^ (((a >> 7) & 7) << 4); }

__global__ void f_prep_w(const float* __restrict__ cw, const float* __restrict__ sw,
                         char* __restrict__ wg) {
  int id = blockIdx.x * 256 + threadIdx.x;
  int j = id & 15, r = (id >> 4) & 127, gi = id >> 11;
  if (gi >= F_GI_TOT) return;
  int g = gi >> 6, k0 = gi & 63;
  int c = r >> 5, r5 = r & 31;
  int f = g * 64 + c * 16 + (r5 & 15);
  const float* src = (r5 < 16) ? cw : sw;
  u32 pk = 0;
  if (f < NFREQ) {
    int k = k0 * 32 + j * 2;
    pk = packbf(src[(size_t)f * 2048 + k], src[(size_t)f * 2048 + k + 1]);
  }
  *(u32*)(wg + (size_t)gi * F_SLABB + r * 64 + j * 4) = pk;
}

__global__ void f_prep_mel(const float* __restrict__ mw, char* __restrict__ mg) {
  int id = blockIdx.x * 256 + threadIdx.x;
  int fp = id & 31, m = (id >> 5) & 127, g = id >> 12;
  if (g >= F_NGRP) return;
  int f = g * 64 + fp * 2;
  float v0 = (f < NFREQ) ? mw[m * NFREQ + f] : 0.f;
  float v1 = (f + 1 < NFREQ) ? mw[m * NFREQ + f + 1] : 0.f;
  int a = m * 128 + fp * 4;
  *(u32*)(mg + (size_t)g * F_MLB + (a ^ ((m & 7) << 4))) = packbf(v0, v1);
}

template <bool PRIM>
__global__ __launch_bounds__(512, 4) void f_mel_main(
    const float* __restrict__ x, const char* __restrict__ wg,
    const char* __restrict__ mg, const float* __restrict__ cw,
    const float* __restrict__ sw, const float* __restrict__ mw,
    float* __restrict__ out) {
  __shared__ __align__(16) char smem[F_LDS_TOT];
  const int tid = threadIdx.x;
  const int lane = tid & 63, wid = tid >> 6;
  const int l15 = lane & 15, l4 = lane >> 4;
  const int bid = blockIdx.x;
  const int b = bid / F_NTT, tt = bid - b * F_NTT;
  const int t0 = tt * F_BT;
  const int c2 = wid >> 1, jh = wid & 1;

  {
    const float* xb = x + (size_t)b * TLEN + (size_t)t0 * 128;
    const int qn = (TLEN - t0 * 128) >> 3;
    for (int it = 0; it < 4; ++it) {
      int q = tid + it * 512;
      if (q < F_XSB / 16) {
        u32 r0 = 0, r1 = 0, r2 = 0, r3 = 0;
        if (q < qn) {
          f32x4 v0 = *(const f32x4*)(xb + q * 8);
          f32x4 v1 = *(const f32x4*)(xb + q * 8 + 4);
          r0 = packbf(v0[0], v0[1]); r1 = packbf(v0[2], v0[3]);
          r2 = packbf(v1[0], v1[1]); r3 = packbf(v1[2], v1[3]);
        }
        int a = q * 16;
        int ph = a ^ ((((a >> 8) + t0) & 7) << 4);
        *(u32x4*)(smem + F_XS_OFF + ph) = (u32x4){r0, r1, r2, r3};
      }
    }
  }

  f32x4 acc[2][3];
  f32x4 mel[6];
#pragma unroll
  for (int i = 0; i < 2; ++i)
#pragma unroll
    for (int j = 0; j < 3; ++j) acc[i][j] = (f32x4){0.f, 0.f, 0.f, 0.f};
#pragma unroll
  for (int i = 0; i < 6; ++i) mel[i] = (f32x4){0.f, 0.f, 0.f, 0.f};

  u32x4 wr_p = {0, 0, 0, 0};
  f32x4 wf0 = {0, 0, 0, 0}, wf1 = {0, 0, 0, 0};
  const int wr_r = tid >> 2, wr_j = tid & 3;
  const int wr_c = wr_r >> 5, wr_r5 = wr_r & 31;

  auto loadW = [&](int gi) {
    if (PRIM) {
      wr_p = *(const u32x4*)(wg + (size_t)gi * F_SLABB + tid * 16);
    } else {
      int g = gi >> 6, k0 = gi & 63;
      int f = g * 64 + wr_c * 16 + (wr_r5 & 15);
      if (f < NFREQ) {
        const float* src = (wr_r5 < 16) ? cw : sw;
        const float* p = src + (size_t)f * 2048 + k0 * 32 + wr_j * 8;
        wf0 = *(const f32x4*)p;
        wf1 = *(const f32x4*)(p + 4);
      } else {
        wf0 = (f32x4){0, 0, 0, 0};
        wf1 = (f32x4){0, 0, 0, 0};
      }
    }
  };

  loadW(0);

  for (int gi = 0; gi < F_GI_TOT; ++gi) {
    const int g = gi >> 6, k0 = gi & 63;
    {
      int a = tid * 16;
      u32x4 v;
      if (PRIM) v = wr_p;
      else v = (u32x4){packbf(wf0[0], wf0[1]), packbf(wf0[2], wf0[3]),
                       packbf(wf1[0], wf1[1]), packbf(wf1[2], wf1[3])};
      *(u32x4*)(smem + F_WL_OFF + f_swzW(a)) = v;
    }
    if (k0 == 0) {
      for (int i = 0; i < 2; ++i) {
        int h = tid + i * 512;
        if (PRIM) {
          u32x4 v = *(const u32x4*)(mg + (size_t)g * F_MLB + h * 16);
          *(u32x4*)(smem + F_ML_OFF + h * 16) = v;
        } else {
          int m = h >> 3, part = h & 7;
          int f0 = g * 64 + part * 8;
          u32 w[4];
#pragma unroll
          for (int e = 0; e < 4; ++e) {
            int f = f0 + e * 2;
            float v0 = (f < NFREQ) ? mw[m * NFREQ + f] : 0.f;
            float v1 = (f + 1 < NFREQ) ? mw[m * NFREQ + f + 1] : 0.f;
            w[e] = packbf(v0, v1);
          }
          int a = m * 128 + part * 16;
          *(u32x4*)(smem + F_ML_OFF + (a ^ ((m & 7) << 4))) = (u32x4){w[0], w[1], w[2], w[3]};
        }
      }
    }
    __syncthreads();
    if (gi + 1 < F_GI_TOT) loadW(gi + 1);

    const int kb = l4 * 16;
    s16x8 bf[3], af[2];
    const int xkey = (k0 >> 2) + t0;
#pragma unroll
    for (int nt = 0; nt < 3; ++nt) {
      const int lt = jh * 48 + nt * 16 + l15;
      const int lb = lt * 256 + k0 * 64 + kb;
      bf[nt] = *(const s16x8*)(smem + F_XS_OFF + (lb ^ (((lt + xkey) & 7) << 4)));
    }
#pragma unroll
    for (int cs = 0; cs < 2; ++cs) {
      const int row = c2 * 32 + cs * 16 + l15;
      af[cs] = *(const s16x8*)(smem + F_WL_OFF + f_swzW(row * 64 + kb));
    }
#pragma unroll
    for (int cs = 0; cs < 2; ++cs)
#pragma unroll
      for (int nt = 0; nt < 3; ++nt)
        acc[cs][nt] = __builtin_amdgcn_mfma_f32_16x16x32_bf16(af[cs], bf[nt],
                                                              acc[cs][nt], 0, 0, 0);

    if (k0 == 63) {
#pragma unroll
      for (int nt = 0; nt < 3; ++nt) {
        f32x4 pc = acc[0][nt], ps = acc[1][nt];
        float p0 = pc[0] * pc[0] + ps[0] * ps[0];
        float p1 = pc[1] * pc[1] + ps[1] * ps[1];
        float p2 = pc[2] * pc[2] + ps[2] * ps[2];
        float p3 = pc[3] * pc[3] + ps[3] * ps[3];
        const int t = jh * 48 + nt * 16 + l15;
        const int a0 = t * 128 + c2 * 32 + l4 * 8;
        const int sw = (t & 7) << 4;
        *(u32*)(smem + F_PL_OFF + (a0 ^ sw)) = packbf(p0, p1);
        *(u32*)(smem + F_PL_OFF + ((a0 + 4) ^ sw)) = packbf(p2, p3);
      }
#pragma unroll
      for (int i = 0; i < 2; ++i)
#pragma unroll
        for (int j = 0; j < 3; ++j) acc[i][j] = (f32x4){0.f, 0.f, 0.f, 0.f};
      __syncthreads();

      const int mrow = wid * 16 + l15;
#pragma unroll
      for (int ks = 0; ks < 2; ++ks) {
        s16x8 a2 = *(const s16x8*)(smem + F_ML_OFF + f_swzR(mrow * 128 + ks * 64 + kb));
#pragma unroll
        for (int n2 = 0; n2 < 6; ++n2) {
          const int tr = n2 * 16 + l15;
          s16x8 b2 = *(const s16x8*)(smem + F_PL_OFF + f_swzR(tr * 128 + ks * 64 + kb));
          mel[n2] = __builtin_amdgcn_mfma_f32_16x16x32_bf16(a2, b2, mel[n2], 0, 0, 0);
        }
      }
    }
    __syncthreads();
  }

#pragma unroll
  for (int n2 = 0; n2 < 6; ++n2) {
    const int t = t0 + n2 * 16 + l15;
    if (t < NFR) {
#pragma unroll
      for (int ii = 0; ii < 4; ++ii) {
        const int m = wid * 16 + l4 * 4 + ii;
        out[(size_t)b * OUT_BT + (size_t)m * NFR + t] = mel[n2][ii];
      }
    }
  }
}

// ================= dispatch =================
extern "C" void kernel_launch(void* const* d_in, const int* in_sizes, int n_in,
                              void* d_out, int out_size, void* d_ws, size_t ws_size,
                              hipStream_t stream) {
  if (n_in < 4) return;
  const float* x  = (const float*)d_in[0];
  const float* cw = (const float*)d_in[1];
  const float* sw = (const float*)d_in[2];
  const float* mw = (const float*)d_in[3];
  float* out = (float*)d_out;
  char* ws = (char*)d_ws;

  int nchunks = 0, tcap = 0;
  int cstart[3], ctb[3];
  if (d_ws && ws_size >= TIER1_NEED) {
    nchunks = 1; tcap = 5376;
    cstart[0] = 0; ctb[0] = 21;
  } else if (d_ws && ws_size >= TIER2_NEED) {
    nchunks = 2; tcap = 2816;
    cstart[0] = 0; ctb[0] = 11; cstart[1] = 2816; ctb[1] = 10;
  } else if (d_ws && ws_size >= TIER3_NEED) {
    nchunks = 3; tcap = 1792;
    cstart[0] = 0; ctb[0] = 7; cstart[1] = 1792; ctb[1] = 7;
    cstart[2] = 3584; ctb[2] = 7;
  }

  if (nchunks > 0) {
    char* wg = ws;
    char* mg = ws + MCAN_OFF;
    char* P  = ws + P_OFF;
    prep_wcan<<<9216, 256, 0, stream>>>(cw, sw, wg);
    prep_mcan<<<288, 256, 0, stream>>>(mw, mg);
    for (int c = 0; c < nchunks; ++c) {
      dim3 g1(ctb[c], 9, NB);
      k1_power<<<g1, 512, 0, stream>>>(x, wg, P, cstart[c], tcap);
      dim3 g2(ctb[c] * 4, NB);
      k2_mel<<<g2, 256, 0, stream>>>(P, mg, out, cstart[c], tcap);
    }
    return;
  }

  // ---- fused fallback (proven R3 path) ----
  const bool prim = (d_ws != nullptr) && (ws_size >= (size_t)F_WS_NEED);
  if (prim) {
    f_prep_w<<<F_GI_TOT * 2048 / 256, 256, 0, stream>>>(cw, sw, ws);
    f_prep_mel<<<F_NGRP * 4096 / 256, 256, 0, stream>>>(mw, ws + F_WS_MG);
    f_mel_main<true><<<NB * F_NTT, 512, 0, stream>>>(x, ws, ws + F_WS_MG,
                                                     cw, sw, mw, out);
  } else {
    f_mel_main<false><<<NB * F_NTT, 512, 0, stream>>>(x, nullptr, nullptr,
                                                      cw, sw, mw, out);
  }
}

// Round 6
// 411.812 us; speedup vs baseline: 1.0690x; 1.0690x over previous
//
#include <hip/hip_runtime.h>
#include <stdint.h>

// ================= problem constants =================
#define NB 8
#define TLEN 661376              // samples per batch
#define NFR 5152                 // frames
#define NFREQ 1025
#define NMEL 128
#define NFRP 5376                // padded frames (21 * 256)
#define OUT_BT (NMEL * NFR)

typedef unsigned int u32;
typedef float f32x4 __attribute__((ext_vector_type(4)));
typedef short s16x8 __attribute__((ext_vector_type(8)));
typedef u32 u32x4 __attribute__((ext_vector_type(4)));

__device__ __forceinline__ u32 f2bf(float f) {
  u32 u = __float_as_uint(f);
  return (u + 0x7FFFu + ((u >> 16) & 1u)) >> 16;   // RNE
}
__device__ __forceinline__ u32 packbf(float a, float b) {
  return f2bf(a) | (f2bf(b) << 16);
}
// Raw barrier with explicit LDS drain; keeps global prefetch loads in flight.
__device__ __forceinline__ void bar_lgkm() {
  asm volatile("s_waitcnt lgkmcnt(0)" ::: "memory");
  __builtin_amdgcn_s_barrier();
  __builtin_amdgcn_sched_barrier(0);
}

// ================= decoupled-path workspace =================
// W canonical: [g 0..8][k 0..63][fr 0..15][l4 0..3][l15 0..15][16B]
#define WCAN_BYTES 9437184        // 9*64*16*1024
#define MCAN_OFF   9437184
#define MCAN_BYTES 294912         // 36*8*1024
#define P_OFF      9732096
#define P_ROWB     2304           // 1152 freqs * 2B
// tiers
#define TIER1_NEED 108822528ULL   // P t-capacity 5376 (1 chunk)
#define TIER2_NEED 61636608ULL    // 2816 (2 chunks)
#define TIER3_NEED 42762240ULL    // 1792 (3 chunks)

// ---- prep: cos/sin fp32 -> bf16 canonical MFMA-A fragments ----
__global__ void prep_wcan(const float* __restrict__ cw, const float* __restrict__ sw,
                          char* __restrict__ wg) {
  int id = blockIdx.x * 256 + threadIdx.x;         // one u32 each
  int jp = id & 3, l15 = (id >> 2) & 15, l4 = (id >> 6) & 3;
  int fr = (id >> 8) & 15, k = (id >> 12) & 63, g = id >> 18;
  if (g >= 9) return;
  int freq = g * 128 + (fr >> 1) * 16 + l15;
  const float* src = (fr & 1) ? sw : cw;
  u32 pk = 0;
  if (freq < NFREQ) {
    int smp = k * 32 + l4 * 8 + jp * 2;
    pk = packbf(src[(size_t)freq * 2048 + smp], src[(size_t)freq * 2048 + smp + 1]);
  }
  *(u32*)(wg + (size_t)id * 4) = pk;
}

// ---- prep: mel fp32 -> bf16 canonical fragments [ks 0..35][fr 0..7][l4][l15][16B] ----
__global__ void prep_mcan(const float* __restrict__ mw, char* __restrict__ mg) {
  int id = blockIdx.x * 256 + threadIdx.x;
  if (id >= 73728) return;
  int jp = id & 3, l15 = (id >> 2) & 15, l4 = (id >> 6) & 3;
  int fr = (id >> 8) & 7, ks = id >> 11;
  int m = fr * 16 + l15;
  int f = ks * 32 + l4 * 8 + jp * 2;
  float v0 = (f < NFREQ) ? mw[(size_t)m * NFREQ + f] : 0.f;
  float v1 = (f + 1 < NFREQ) ? mw[(size_t)m * NFREQ + f + 1] : 0.f;
  *(u32*)(mg + (size_t)id * 4) = packbf(v0, v1);
}

// ================= K1: power spectrum =================
// grid (tb, 9, 8), 512 threads. Block: 256 W-rows x 256 frames.
// LDS: x 69376 B + W 3-deep ring 3*16384 = 118528 B (1 block/CU).
// 4 sub-phases per K-iter, pinned by sched_barrier(0): each sub interleaves
// 8 MFMA with ~3 LDS reads + 1 staging op so matrix & LDS pipes overlap.
#define K1_X 69376
#define K1_LDS 118528
__global__ __launch_bounds__(512, 2) void k1_power(
    const float* __restrict__ x, const char* __restrict__ wg,
    char* __restrict__ P, int tstart, int tcap) {
  __shared__ __align__(16) char smem[K1_LDS];
  const int tid = threadIdx.x;
  const int lane = tid & 63, wid = tid >> 6;
  const int l15 = lane & 15, l4 = lane >> 4;
  const int fw = wid & 3, tw = wid >> 2;           // freq-wave, t-wave
  const int tb = blockIdx.x, g = blockIdx.y, b = blockIdx.z;
  const int t0 = tstart + tb * 256;

  // ---- stage x tile fp32->bf16, XOR swizzle on logical byte addr ----
  {
    const float* xb = x + (size_t)b * TLEN;
    const int sbase = t0 * 128;
#pragma unroll
    for (int i = 0; i < 9; ++i) {
      int q = tid + i * 512;
      if (q < 4336) {
        int s0 = sbase + q * 8;
        u32 r0, r1, r2, r3;
        if (s0 + 8 <= TLEN) {
          f32x4 v0 = *(const f32x4*)(xb + s0);
          f32x4 v1 = *(const f32x4*)(xb + s0 + 4);
          r0 = packbf(v0[0], v0[1]); r1 = packbf(v0[2], v0[3]);
          r2 = packbf(v1[0], v1[1]); r3 = packbf(v1[2], v1[3]);
        } else {
          float e[8];
#pragma unroll
          for (int j = 0; j < 8; ++j) { int s = s0 + j; e[j] = (s < TLEN) ? xb[s] : 0.f; }
          r0 = packbf(e[0], e[1]); r1 = packbf(e[2], e[3]);
          r2 = packbf(e[4], e[5]); r3 = packbf(e[6], e[7]);
        }
        int lb = q * 16;
        *(u32x4*)(smem + (lb ^ (((lb >> 8) & 7) << 4))) = (u32x4){r0, r1, r2, r3};
      }
    }
  }

  f32x4 acc[4][8];
#pragma unroll
  for (int i = 0; i < 4; ++i)
#pragma unroll
    for (int j = 0; j < 8; ++j) acc[i][j] = (f32x4){0.f, 0.f, 0.f, 0.f};

  const char* wslab = wg + (size_t)g * (64 * 16384);
  char* ring = smem + K1_X;

  // frag address pieces (bfkey = lt&7 == l15&7, uniform across nt)
  const int bfb = (tw * 128 + l15) * 256 + l4 * 16;
  const int afoff = fw * 4096 + l4 * 256 + l15 * 16;

  // ---- prologue: slabs 0,1 -> ring; slab 2 -> regs (wrA) ----
  {
    u32x4 a0 = *(const u32x4*)(wslab + tid * 16);
    u32x4 a1 = *(const u32x4*)(wslab + tid * 16 + 8192);
    u32x4 b0 = *(const u32x4*)(wslab + 16384 + tid * 16);
    u32x4 b1 = *(const u32x4*)(wslab + 16384 + tid * 16 + 8192);
    *(u32x4*)(ring + tid * 16) = a0;
    *(u32x4*)(ring + tid * 16 + 8192) = a1;
    *(u32x4*)(ring + 16384 + tid * 16) = b0;
    *(u32x4*)(ring + 16384 + tid * 16 + 8192) = b1;
  }
  u32x4 wrA0 = *(const u32x4*)(wslab + 2 * 16384 + tid * 16);
  u32x4 wrA1 = *(const u32x4*)(wslab + 2 * 16384 + tid * 16 + 8192);
  u32x4 wrB0 = {0, 0, 0, 0}, wrB1 = {0, 0, 0, 0};
  bar_lgkm();                                       // x + slabs 0,1 visible

  s16x8 afA[4], afB[4], bf[8];
  {
    const int key0 = (l15 & 7) << 4;
#pragma unroll
    for (int q = 0; q < 4; ++q)
      afA[q] = *(const s16x8*)(ring + afoff + q * 1024);
#pragma unroll
    for (int nt = 0; nt < 8; ++nt)
      bf[nt] = *(const s16x8*)(smem + ((bfb + nt * 4096) ^ key0));
  }
  bar_lgkm();   // frag(0) reads drained before any ring overwrite

  // iter k: MFMA(k) from afc/bf; read frags(k+1) (af->afn dbuf, bf in place);
  // ds_write slab k+2 from wc; global-load slab k+3 into wn.
  auto iter = [&](int k, s16x8 (&afc)[4], s16x8 (&afn)[4],
                  u32x4& wc0, u32x4& wc1, u32x4& wn0, u32x4& wn1) {
    const char* rnext = ring + ((k + 1) % 3) * 16384;
    char* rwr = ring + ((k + 2) % 3) * 16384;
    const int kn = k + 1;
    const int key = ((l15 + (kn >> 2)) & 7) << 4;
    const int ab = bfb + kn * 64;
#pragma unroll
    for (int q = 0; q < 4; ++q) {
      __builtin_amdgcn_s_setprio(1);
#pragma unroll
      for (int m4 = 0; m4 < 4; ++m4) {
        acc[m4][2 * q] = __builtin_amdgcn_mfma_f32_16x16x32_bf16(
            afc[m4], bf[2 * q], acc[m4][2 * q], 0, 0, 0);
        acc[m4][2 * q + 1] = __builtin_amdgcn_mfma_f32_16x16x32_bf16(
            afc[m4], bf[2 * q + 1], acc[m4][2 * q + 1], 0, 0, 0);
      }
      __builtin_amdgcn_s_setprio(0);
      if (kn < 64) {
        bf[2 * q] = *(const s16x8*)(smem + ((ab + (2 * q) * 4096) ^ key));
        bf[2 * q + 1] = *(const s16x8*)(smem + ((ab + (2 * q + 1) * 4096) ^ key));
        afn[q] = *(const s16x8*)(rnext + afoff + q * 1024);
      }
      if (q == 0 && k + 2 < 64) *(u32x4*)(rwr + tid * 16) = wc0;
      if (q == 1 && k + 2 < 64) *(u32x4*)(rwr + tid * 16 + 8192) = wc1;
      if (q == 2 && k + 3 < 64)
        wn0 = *(const u32x4*)(wslab + (size_t)(k + 3) * 16384 + tid * 16);
      if (q == 3 && k + 3 < 64)
        wn1 = *(const u32x4*)(wslab + (size_t)(k + 3) * 16384 + tid * 16 + 8192);
      __builtin_amdgcn_sched_barrier(0);
    }
    asm volatile("s_waitcnt lgkmcnt(0)" ::: "memory");
    __builtin_amdgcn_s_barrier();
    __builtin_amdgcn_sched_barrier(0);
  };

  for (int kk = 0; kk < 32; ++kk) {
    iter(2 * kk, afA, afB, wrA0, wrA1, wrB0, wrB1);
    iter(2 * kk + 1, afB, afA, wrB0, wrB1, wrA0, wrA1);
  }

  // ---- P = c^2+s^2 -> bf16 -> LDS (reuse ring region) -> global [t][f] ----
  char* plds = smem + K1_X;
#pragma unroll
  for (int h = 0; h < 2; ++h) {
    if (tw == h) {
#pragma unroll
      for (int q = 0; q < 2; ++q)
#pragma unroll
        for (int nt = 0; nt < 8; ++nt) {
          f32x4 c = acc[q * 2][nt], s = acc[q * 2 + 1][nt];
          float p0 = c[0] * c[0] + s[0] * s[0];
          float p1 = c[1] * c[1] + s[1] * s[1];
          float p2 = c[2] * c[2] + s[2] * s[2];
          float p3 = c[3] * c[3] + s[3] * s[3];
          int lt = nt * 16 + l15;                   // row within this 128-t half
          int fl = fw * 32 + q * 16 + l4 * 4;
          int a = lt * 256 + fl * 2;
          int sw = (lt & 7) << 4;
          *(u32*)(plds + (a ^ sw)) = packbf(p0, p1);
          *(u32*)(plds + ((a + 4) ^ sw)) = packbf(p2, p3);
        }
    }
    bar_lgkm();
#pragma unroll
    for (int i = 0; i < 4; ++i) {
      int lin = (tid + i * 512) * 16;
      u32x4 v = *(const u32x4*)(plds + (lin ^ (((lin >> 8) & 7) << 4)));
      int tc = tb * 256 + h * 128 + (lin >> 8);
      *(u32x4*)(P + ((size_t)b * tcap + tc) * P_ROWB + g * 256 + (lin & 255)) = v;
    }
    bar_lgkm();
  }
}

// ================= K2: mel GEMM =================
// grid (tb64, 8), 256 threads (4 waves, m-split). Block: 128 m x 64 t, K = 1152.
__global__ __launch_bounds__(256, 4) void k2_mel(
    const char* __restrict__ P, const char* __restrict__ mg,
    float* __restrict__ out, int tstart, int tcap) {
  __shared__ __align__(16) char sm[4096];
  const int tid = threadIdx.x;
  const int lane = tid & 63, wid = tid >> 6;
  const int l15 = lane & 15, l4 = lane >> 4;
  const int tb = blockIdx.x, b = blockIdx.y;
  const int tz = tb * 64;                           // chunk-local t base

  const int st_t = tid >> 2, st_fo = tid & 3;       // staging map: 64t x 4 granules
  const char* prow = P + ((size_t)b * tcap + tz + st_t) * P_ROWB + st_fo * 16;

  f32x4 acc[2][4];
#pragma unroll
  for (int i = 0; i < 2; ++i)
#pragma unroll
    for (int j = 0; j < 4; ++j) acc[i][j] = (f32x4){0.f, 0.f, 0.f, 0.f};

  u32x4 pr = *(const u32x4*)prow;
  const int lw = (st_t * 64 + st_fo * 16) ^ ((st_t & 7) << 4);
  const int afo = l4 * 256 + l15 * 16;

  for (int ks = 0; ks < 36; ++ks) {
    *(u32x4*)(sm + lw) = pr;
    bar_lgkm();
    if (ks + 1 < 36) pr = *(const u32x4*)(prow + (ks + 1) * 64);
    s16x8 a0 = *(const s16x8*)(mg + (size_t)(ks * 8 + wid * 2) * 1024 + afo);
    s16x8 a1 = *(const s16x8*)(mg + (size_t)(ks * 8 + wid * 2 + 1) * 1024 + afo);
    s16x8 bf[4];
#pragma unroll
    for (int nt = 0; nt < 4; ++nt) {
      int a = ((nt * 16 + l15) * 64 + l4 * 16) ^ ((l15 & 7) << 4);
      bf[nt] = *(const s16x8*)(sm + a);
    }
#pragma unroll
    for (int nt = 0; nt < 4; ++nt) {
      acc[0][nt] = __builtin_amdgcn_mfma_f32_16x16x32_bf16(a0, bf[nt], acc[0][nt], 0, 0, 0);
      acc[1][nt] = __builtin_amdgcn_mfma_f32_16x16x32_bf16(a1, bf[nt], acc[1][nt], 0, 0, 0);
    }
    bar_lgkm();
  }

#pragma unroll
  for (int nt = 0; nt < 4; ++nt) {
    int t = tstart + tz + nt * 16 + l15;
    if (t < NFR) {
#pragma unroll
      for (int mf = 0; mf < 2; ++mf)
#pragma unroll
        for (int ii = 0; ii < 4; ++ii) {
          int m = wid * 32 + mf * 16 + l4 * 4 + ii;
          out[(size_t)b * OUT_BT + (size_t)m * NFR + t] = acc[mf][nt][ii];
        }
    }
  }
}

// ======================================================================
// ================= fused fallback (R3, proven) ========================
// ======================================================================
#define F_BT 96
#define F_NTT 54
#define F_NGRP 17
#define F_GI_TOT 1088
#define F_SLABB 8192
#define F_XSB 28416
#define F_XS_OFF 0
#define F_WL_OFF 28416
#define F_PL_OFF 36608
#define F_ML_OFF 48896
#define F_LDS_TOT 65280
#define F_WS_MG 8912896
#define F_WS_NEED 9191424
#define F_MLB 16384

__device__ __forceinline__ int f_swzW(int a) { return a ^ (((a >> 6) & 7) << 4); }
__device__ __forceinline__ int f_swzR(int a) { return a ^ (((a >> 7) & 7) << 4); }

__global__ void f_prep_w(const float* __restrict__ cw, const float* __restrict__ sw,
                         char* __restrict__ wg) {
  int id = blockIdx.x * 256 + threadIdx.x;
  int j = id & 15, r = (id >> 4) & 127, gi = id >> 11;
  if (gi >= F_GI_TOT) return;
  int g = gi >> 6, k0 = gi & 63;
  int c = r >> 5, r5 = r & 31;
  int f = g * 64 + c * 16 + (r5 & 15);
  const float* src = (r5 < 16) ? cw : sw;
  u32 pk = 0;
  if (f < NFREQ) {
    int k = k0 * 32 + j * 2;
    pk = packbf(src[(size_t)f * 2048 + k], src[(size_t)f * 2048 + k + 1]);
  }
  *(u32*)(wg + (size_t)gi * F_SLABB + r * 64 + j * 4) = pk;
}

__global__ void f_prep_mel(const float* __restrict__ mw, char* __restrict__ mg) {
  int id = blockIdx.x * 256 + threadIdx.x;
  int fp = id & 31, m = (id >> 5) & 127, g = id >> 12;
  if (g >= F_NGRP) return;
  int f = g * 64 + fp * 2;
  float v0 = (f < NFREQ) ? mw[m * NFREQ + f] : 0.f;
  float v1 = (f + 1 < NFREQ) ? mw[m * NFREQ + f + 1] : 0.f;
  int a = m * 128 + fp * 4;
  *(u32*)(mg + (size_t)g * F_MLB + (a ^ ((m & 7) << 4))) = packbf(v0, v1);
}

template <bool PRIM>
__global__ __launch_bounds__(512, 4) void f_mel_main(
    const float* __restrict__ x, const char* __restrict__ wg,
    const char* __restrict__ mg, const float* __restrict__ cw,
    const float* __restrict__ sw, const float* __restrict__ mw,
    float* __restrict__ out) {
  __shared__ __align__(16) char smem[F_LDS_TOT];
  const int tid = threadIdx.x;
  const int lane = tid & 63, wid = tid >> 6;
  const int l15 = lane & 15, l4 = lane >> 4;
  const int bid = blockIdx.x;
  const int b = bid / F_NTT, tt = bid - b * F_NTT;
  const int t0 = tt * F_BT;
  const int c2 = wid >> 1, jh = wid & 1;

  {
    const float* xb = x + (size_t)b * TLEN + (size_t)t0 * 128;
    const int qn = (TLEN - t0 * 128) >> 3;
    for (int it = 0; it < 4; ++it) {
      int q = tid + it * 512;
      if (q < F_XSB / 16) {
        u32 r0 = 0, r1 = 0, r2 = 0, r3 = 0;
        if (q < qn) {
          f32x4 v0 = *(const f32x4*)(xb + q * 8);
          f32x4 v1 = *(const f32x4*)(xb + q * 8 + 4);
          r0 = packbf(v0[0], v0[1]); r1 = packbf(v0[2], v0[3]);
          r2 = packbf(v1[0], v1[1]); r3 = packbf(v1[2], v1[3]);
        }
        int a = q * 16;
        int ph = a ^ ((((a >> 8) + t0) & 7) << 4);
        *(u32x4*)(smem + F_XS_OFF + ph) = (u32x4){r0, r1, r2, r3};
      }
    }
  }

  f32x4 acc[2][3];
  f32x4 mel[6];
#pragma unroll
  for (int i = 0; i < 2; ++i)
#pragma unroll
    for (int j = 0; j < 3; ++j) acc[i][j] = (f32x4){0.f, 0.f, 0.f, 0.f};
#pragma unroll
  for (int i = 0; i < 6; ++i) mel[i] = (f32x4){0.f, 0.f, 0.f, 0.f};

  u32x4 wr_p = {0, 0, 0, 0};
  f32x4 wf0 = {0, 0, 0, 0}, wf1 = {0, 0, 0, 0};
  const int wr_r = tid >> 2, wr_j = tid & 3;
  const int wr_c = wr_r >> 5, wr_r5 = wr_r & 31;

  auto loadW = [&](int gi) {
    if (PRIM) {
      wr_p = *(const u32x4*)(wg + (size_t)gi * F_SLABB + tid * 16);
    } else {
      int g = gi >> 6, k0 = gi & 63;
      int f = g * 64 + wr_c * 16 + (wr_r5 & 15);
      if (f < NFREQ) {
        const float* src = (wr_r5 < 16) ? cw : sw;
        const float* p = src + (size_t)f * 2048 + k0 * 32 + wr_j * 8;
        wf0 = *(const f32x4*)p;
        wf1 = *(const f32x4*)(p + 4);
      } else {
        wf0 = (f32x4){0, 0, 0, 0};
        wf1 = (f32x4){0, 0, 0, 0};
      }
    }
  };

  loadW(0);

  for (int gi = 0; gi < F_GI_TOT; ++gi) {
    const int g = gi >> 6, k0 = gi & 63;
    {
      int a = tid * 16;
      u32x4 v;
      if (PRIM) v = wr_p;
      else v = (u32x4){packbf(wf0[0], wf0[1]), packbf(wf0[2], wf0[3]),
                       packbf(wf1[0], wf1[1]), packbf(wf1[2], wf1[3])};
      *(u32x4*)(smem + F_WL_OFF + f_swzW(a)) = v;
    }
    if (k0 == 0) {
      for (int i = 0; i < 2; ++i) {
        int h = tid + i * 512;
        if (PRIM) {
          u32x4 v = *(const u32x4*)(mg + (size_t)g * F_MLB + h * 16);
          *(u32x4*)(smem + F_ML_OFF + h * 16) = v;
        } else {
          int m = h >> 3, part = h & 7;
          int f0 = g * 64 + part * 8;
          u32 w[4];
#pragma unroll
          for (int e = 0; e < 4; ++e) {
            int f = f0 + e * 2;
            float v0 = (f < NFREQ) ? mw[m * NFREQ + f] : 0.f;
            float v1 = (f + 1 < NFREQ) ? mw[m * NFREQ + f + 1] : 0.f;
            w[e] = packbf(v0, v1);
          }
          int a = m * 128 + part * 16;
          *(u32x4*)(smem + F_ML_OFF + (a ^ ((m & 7) << 4))) = (u32x4){w[0], w[1], w[2], w[3]};
        }
      }
    }
    __syncthreads();
    if (gi + 1 < F_GI_TOT) loadW(gi + 1);

    const int kb = l4 * 16;
    s16x8 bf[3], af[2];
    const int xkey = (k0 >> 2) + t0;
#pragma unroll
    for (int nt = 0; nt < 3; ++nt) {
      const int lt = jh * 48 + nt * 16 + l15;
      const int lb = lt * 256 + k0 * 64 + kb;
      bf[nt] = *(const s16x8*)(smem + F_XS_OFF + (lb ^ (((lt + xkey) & 7) << 4)));
    }
#pragma unroll
    for (int cs = 0; cs < 2; ++cs) {
      const int row = c2 * 32 + cs * 16 + l15;
      af[cs] = *(const s16x8*)(smem + F_WL_OFF + f_swzW(row * 64 + kb));
    }
#pragma unroll
    for (int cs = 0; cs < 2; ++cs)
#pragma unroll
      for (int nt = 0; nt < 3; ++nt)
        acc[cs][nt] = __builtin_amdgcn_mfma_f32_16x16x32_bf16(af[cs], bf[nt],
                                                              acc[cs][nt], 0, 0, 0);

    if (k0 == 63) {
#pragma unroll
      for (int nt = 0; nt < 3; ++nt) {
        f32x4 pc = acc[0][nt], ps = acc[1][nt];
        float p0 = pc[0] * pc[0] + ps[0] * ps[0];
        float p1 = pc[1] * pc[1] + ps[1] * ps[1];
        float p2 = pc[2] * pc[2] + ps[2] * ps[2];
        float p3 = pc[3] * pc[3] + ps[3] * ps[3];
        const int t = jh * 48 + nt * 16 + l15;
        const int a0 = t * 128 + c2 * 32 + l4 * 8;
        const int sw = (t & 7) << 4;
        *(u32*)(smem + F_PL_OFF + (a0 ^ sw)) = packbf(p0, p1);
        *(u32*)(smem + F_PL_OFF + ((a0 + 4) ^ sw)) = packbf(p2, p3);
      }
#pragma unroll
      for (int i = 0; i < 2; ++i)
#pragma unroll
        for (int j = 0; j < 3; ++j) acc[i][j] = (f32x4){0.f, 0.f, 0.f, 0.f};
      __syncthreads();

      const int mrow = wid * 16 + l15;
#pragma unroll
      for (int ks = 0; ks < 2; ++ks) {
        s16x8 a2 = *(const s16x8*)(smem + F_ML_OFF + f_swzR(mrow * 128 + ks * 64 + kb));
#pragma unroll
        for (int n2 = 0; n2 < 6; ++n2) {
          const int tr = n2 * 16 + l15;
          s16x8 b2 = *(const s16x8*)(smem + F_PL_OFF + f_swzR(tr * 128 + ks * 64 + kb));
          mel[n2] = __builtin_amdgcn_mfma_f32_16x16x32_bf16(a2, b2, mel[n2], 0, 0, 0);
        }
      }
    }
    __syncthreads();
  }

#pragma unroll
  for (int n2 = 0; n2 < 6; ++n2) {
    const int t = t0 + n2 * 16 + l15;
    if (t < NFR) {
#pragma unroll
      for (int ii = 0; ii < 4; ++ii) {
        const int m = wid * 16 + l4 * 4 + ii;
        out[(size_t)b * OUT_BT + (size_t)m * NFR + t] = mel[n2][ii];
      }
    }
  }
}

// ================= dispatch =================
extern "C" void kernel_launch(void* const* d_in, const int* in_sizes, int n_in,
                              void* d_out, int out_size, void* d_ws, size_t ws_size,
                              hipStream_t stream) {
  if (n_in < 4) return;
  const float* x  = (const float*)d_in[0];
  const float* cw = (const float*)d_in[1];
  const float* sw = (const float*)d_in[2];
  const float* mw = (const float*)d_in[3];
  float* out = (float*)d_out;
  char* ws = (char*)d_ws;

  int nchunks = 0, tcap = 0;
  int cstart[3], ctb[3];
  if (d_ws && ws_size >= TIER1_NEED) {
    nchunks = 1; tcap = 5376;
    cstart[0] = 0; ctb[0] = 21;
  } else if (d_ws && ws_size >= TIER2_NEED) {
    nchunks = 2; tcap = 2816;
    cstart[0] = 0; ctb[0] = 11; cstart[1] = 2816; ctb[1] = 10;
  } else if (d_ws && ws_size >= TIER3_NEED) {
    nchunks = 3; tcap = 1792;
    cstart[0] = 0; ctb[0] = 7; cstart[1] = 1792; ctb[1] = 7;
    cstart[2] = 3584; ctb[2] = 7;
  }

  if (nchunks > 0) {
    char* wg = ws;
    char* mg = ws + MCAN_OFF;
    char* P  = ws + P_OFF;
    prep_wcan<<<9216, 256, 0, stream>>>(cw, sw, wg);
    prep_mcan<<<288, 256, 0, stream>>>(mw, mg);
    for (int c = 0; c < nchunks; ++c) {
      dim3 g1(ctb[c], 9, NB);
      k1_power<<<g1, 512, 0, stream>>>(x, wg, P, cstart[c], tcap);
      dim3 g2(ctb[c] * 4, NB);
      k2_mel<<<g2, 256, 0, stream>>>(P, mg, out, cstart[c], tcap);
    }
    return;
  }

  // ---- fused fallback (proven R3 path) ----
  const bool prim = (d_ws != nullptr) && (ws_size >= (size_t)F_WS_NEED);
  if (prim) {
    f_prep_w<<<F_GI_TOT * 2048 / 256, 256, 0, stream>>>(cw, sw, ws);
    f_prep_mel<<<F_NGRP * 4096 / 256, 256, 0, stream>>>(mw, ws + F_WS_MG);
    f_mel_main<true><<<NB * F_NTT, 512, 0, stream>>>(x, ws, ws + F_WS_MG,
                                                     cw, sw, mw, out);
  } else {
    f_mel_main<false><<<NB * F_NTT, 512, 0, stream>>>(x, nullptr, nullptr,
                                                      cw, sw, mw, out);
  }
}